// Round 5
// baseline (18007.353 us; speedup 1.0000x reference)
//
#include <hip/hip_runtime.h>

typedef __attribute__((ext_vector_type(8))) short short8;
typedef __attribute__((ext_vector_type(4))) float f32x4;

#define BDIM 256
#define NWG 256

constexpr int Bsz = 128;   // batch
constexpr int Tlen = 512;  // seq len
constexpr int Hd = 1024;   // hidden
constexpr int Ed = 512;    // embed
constexpr int K0 = 1536;   // L0 fused K = H + E
constexpr int K1 = 2048;   // L1 fused K = H + H
constexpr int BK = 128;    // K-chunk

__device__ __forceinline__ float b2f(unsigned short u) {
  return __uint_as_float(((unsigned int)u) << 16);
}
__device__ __forceinline__ unsigned short f2b(float f) {
  unsigned int u = __float_as_uint(f);
  u = (u + 0x7FFFu + ((u >> 16) & 1u)) >> 16;
  return (unsigned short)u;
}

__global__ void __launch_bounds__(BDIM) gru_step(
    const int* __restrict__ src,
    const float* __restrict__ emb,
    const float* __restrict__ wih0,
    const float* __restrict__ whh0,
    const float* __restrict__ bih0,
    const float* __restrict__ bhh0,
    const float* __restrict__ wih1,
    const float* __restrict__ whh1,
    const float* __restrict__ bih1,
    const float* __restrict__ bhh1,
    float* __restrict__ dout,
    unsigned short* __restrict__ A0,
    unsigned short* __restrict__ A1,
    int r)
{
  __shared__ __align__(16) unsigned short smA[64 * BK];  // 16 KB
  __shared__ __align__(16) unsigned short smB[48 * BK];  // 12 KB

  const int wg = blockIdx.x;
  const int layer = wg >> 7;
  const bool active = (layer == 0) ? (r < 512) : (r >= 1);
  if (!active) return;

  const int mh = wg & 1;          // M-half
  const int c = (wg & 127) >> 1;  // gate-triple index 0..63
  const int R0 = mh * 64;
  const int J0 = c * 16;

  const int Ksz = layer ? K1 : K0;
  const int nch = Ksz / BK;            // 12 or 16
  const int xK = layer ? 1024 : 512;   // w_ih row length
  unsigned short* Ab = layer ? A1 : A0;
  const float* Whh = layer ? whh1 : whh0;
  const float* Wih = layer ? wih1 : wih0;
  const float* bih = layer ? bih1 : bih0;
  const float* bhh = layer ? bhh1 : bhh0;

  // first active round for this layer: h == 0, h-part chunks skipped,
  // so NO d_ws location is read before being written in this launch.
  const bool first = (layer == 0) ? (r == 0) : (r == 1);

  const int tid = threadIdx.x;
  const int w = tid >> 6;      // wave 0..3 — wave w owns M-block w (16 rows)
  const int lane = tid & 63;
  const int lrow = lane >> 4;  // quad 0..3
  const int lcol = lane & 15;

  const int par = r & 1;
  const unsigned short* Acur = Ab + par * (Bsz * Ksz);
  unsigned short* Anext = Ab + (par ^ 1) * (Bsz * Ksz);

  // per-lane bias values for this lane's output column (fp32)
  const int col = J0 + lcol;
  const float bir = bih[col],        bhr = bhh[col];
  const float biz = bih[1024 + col], bhz = bhh[1024 + col];
  const float bin = bih[2048 + col], bhn = bhh[2048 + col];

  f32x4 ar = (f32x4){0.f, 0.f, 0.f, 0.f};
  f32x4 az = (f32x4){0.f, 0.f, 0.f, 0.f};
  f32x4 anh = (f32x4){0.f, 0.f, 0.f, 0.f};
  f32x4 anx = (f32x4){0.f, 0.f, 0.f, 0.f};

  for (int ch = first ? 8 : 0; ch < nch; ++ch) {
    const int k0 = ch * BK;

    // ---- stage A tile: 64 rows x 128 k (ring is already bf16)
#pragma unroll
    for (int s = 0; s < 4; ++s) {
      const int idx = tid + s * 256;      // 0..1023 short8 slots
      const int rowi = idx >> 4;          // 0..63
      const int k8 = idx & 15;            // 0..15
      short8 v = *(const short8*)(Acur + (R0 + rowi) * Ksz + k0 + k8 * 8);
      *(short8*)(smA + rowi * BK + k8 * 8) = v;
    }
    // ---- stage B tile: 48 W-rows x 128 k, fp32 global -> bf16 LDS
#pragma unroll
    for (int s = 0; s < 3; ++s) {
      const int idx = tid + s * 256;      // 0..767 short8 slots
      const int tr = idx >> 4;            // tile row 0..47
      const int k8 = idx & 15;
      const int gate = tr >> 4;
      const int wrow = gate * 1024 + J0 + (tr & 15);
      const float* gp = (k0 < 1024)
          ? (Whh + wrow * 1024 + k0 + k8 * 8)
          : (Wih + wrow * xK + (k0 - 1024) + k8 * 8);
      const float4 v0 = ((const float4*)gp)[0];
      const float4 v1 = ((const float4*)gp)[1];
      short8 o;
      o[0] = (short)f2b(v0.x); o[1] = (short)f2b(v0.y);
      o[2] = (short)f2b(v0.z); o[3] = (short)f2b(v0.w);
      o[4] = (short)f2b(v1.x); o[5] = (short)f2b(v1.y);
      o[6] = (short)f2b(v1.z); o[7] = (short)f2b(v1.w);
      *(short8*)(smB + tr * BK + k8 * 8) = o;
    }
    __syncthreads();

    const bool hpart = (k0 < 1024);
#pragma unroll
    for (int ks = 0; ks < 4; ++ks) {
      const int ke = ks * 32 + lrow * 8;
      short8 a  = *(const short8*)(smA + (w * 16 + lcol) * BK + ke);
      short8 br = *(const short8*)(smB + (lcol) * BK + ke);
      short8 bz = *(const short8*)(smB + (16 + lcol) * BK + ke);
      short8 bn = *(const short8*)(smB + (32 + lcol) * BK + ke);
      ar = __builtin_amdgcn_mfma_f32_16x16x32_bf16(a, br, ar, 0, 0, 0);
      az = __builtin_amdgcn_mfma_f32_16x16x32_bf16(a, bz, az, 0, 0, 0);
      if (hpart)
        anh = __builtin_amdgcn_mfma_f32_16x16x32_bf16(a, bn, anh, 0, 0, 0);
      else
        anx = __builtin_amdgcn_mfma_f32_16x16x32_bf16(a, bn, anx, 0, 0, 0);
    }
    __syncthreads();
  }

  // ---- epilogue: wave w owns rows R0+w*16 .. +15, cols J0..J0+15
  const bool lastw = (layer == 0) ? (r == 511) : (r == 512);
#pragma unroll
  for (int i = 0; i < 4; ++i) {
    const int row = R0 + w * 16 + lrow * 4 + i;
    float rg = ar[i] + bir + bhr;
    rg = 1.f / (1.f + __expf(-rg));
    float zg = az[i] + biz + bhz;
    zg = 1.f / (1.f + __expf(-zg));
    const float ng = tanhf((anx[i] + bin) + rg * (anh[i] + bhn));
    const float hold = first ? 0.f : b2f(Acur[row * Ksz + col]);
    const float hnew = (1.f - zg) * ng + zg * hold;
    const unsigned short hb = f2b(hnew);
    Anext[row * Ksz + col] = hb;  // h-part of next-round A
    if (layer == 0)               // y0 slot for L1's next round
      A1[(par ^ 1) * (Bsz * K1) + row * K1 + 1024 + col] = hb;
    if (lastw)
      dout[layer * (Bsz * Hd) + row * Hd + col] = hnew;  // fp32 out
  }

  // ---- gather x_{r+1} into next A0 x-part (layer 0 only), fp32 emb -> bf16
  if (layer == 0 && r < 511) {
    const int grow = R0 + (tid >> 2);
    const int e = c * 8 + (tid & 3) * 2;
    const int sv = src[grow * Tlen + (r + 1)];
    const float2 xv = *(const float2*)(emb + sv * Ed + e);
    const unsigned int pv = ((unsigned int)f2b(xv.y) << 16) | (unsigned int)f2b(xv.x);
    *(unsigned int*)(Anext + grow * Ksz + 1024 + e) = pv;
  }
}

// x_0 gather into A0 slot0 x-part (fp32 emb -> bf16 ring).
__global__ void prime_k(const int* __restrict__ src,
                        const float* __restrict__ emb,
                        unsigned short* __restrict__ A0) {
  const int tid = blockIdx.x * blockDim.x + threadIdx.x;  // 32768 threads
  const int row = tid >> 8;        // 0..127
  const int e = (tid & 255) * 2;   // 0..510 step 2
  const int sv = src[row * Tlen];
  const float2 xv = *(const float2*)(emb + sv * Ed + e);
  const unsigned int pv = ((unsigned int)f2b(xv.y) << 16) | (unsigned int)f2b(xv.x);
  *(unsigned int*)(A0 + row * K0 + 1024 + e) = pv;
}

extern "C" void kernel_launch(void* const* d_in, const int* in_sizes, int n_in,
                              void* d_out, int out_size, void* d_ws, size_t ws_size,
                              hipStream_t stream) {
  const int* src = (const int*)d_in[0];
  const float* emb = (const float*)d_in[1];
  const float* wih0 = (const float*)d_in[2];
  const float* whh0 = (const float*)d_in[3];
  const float* bih0 = (const float*)d_in[4];
  const float* bhh0 = (const float*)d_in[5];
  const float* wih1 = (const float*)d_in[6];
  const float* whh1 = (const float*)d_in[7];
  const float* bih1 = (const float*)d_in[8];
  const float* bhh1 = (const float*)d_in[9];
  float* dout = (float*)d_out;

  char* w = (char*)d_ws;
  unsigned short* A0 = (unsigned short*)w;              // 2*128*1536*2 = 786432 B
  unsigned short* A1 = (unsigned short*)(w + 786432);   // 2*128*2048*2 = 1048576 B
  // total ws use: 1835008 B

  hipLaunchKernelGGL(prime_k, dim3(128), dim3(256), 0, stream, src, emb, A0);

  for (int r = 0; r < 513; ++r) {
    hipLaunchKernelGGL(gru_step, dim3(NWG), dim3(BDIM), 0, stream,
                       src, emb, wih0, whh0, bih0, bhh0,
                       wih1, whh1, bih1, bhh1, dout, A0, A1, r);
  }
}

// Round 7
// 13720.163 us; speedup vs baseline: 1.3125x; 1.3125x over previous
//
#include <hip/hip_runtime.h>

typedef __attribute__((ext_vector_type(8))) short short8;
typedef __attribute__((ext_vector_type(4))) float f32x4;

constexpr int Bsz = 128;   // batch
constexpr int Tlen = 512;  // seq len
constexpr int Hd = 1024;   // hidden
constexpr int K0 = 1024;   // L0 ring K (h only; x handled via P table)
constexpr int K1 = 2048;   // L1 ring K = [h1 | y0]
constexpr int BK = 128;    // K-chunk

__device__ __forceinline__ unsigned short f2b(float f) {
  unsigned int u = __float_as_uint(f);
  u = (u + 0x7FFFu + ((u >> 16) & 1u)) >> 16;
  return (unsigned short)u;
}
__device__ __forceinline__ float b2f(unsigned short u) {
  return __uint_as_float(((unsigned int)u) << 16);
}

// ---------------- per-step kernel ----------------
// 256 WGs: layer = wg>>7, mh = wg&1 (64 rows), c = (wg&127)>>1 (16 h-cols, 3 gates).
// Waves K-split each 128-chunk (wave w: k-seg w*32); cross-wave LDS reduce once/step.
__global__ void __launch_bounds__(256, 1) gru_step(
    const int* __restrict__ src,
    const float* __restrict__ P,             // [512][3072] fp32: emb @ wih0^T + bih0
    const unsigned short* __restrict__ Whh0b, // [3072][1024] bf16
    const unsigned short* __restrict__ Whh1b, // [3072][1024] bf16
    const unsigned short* __restrict__ Wih1b, // [3072][1024] bf16
    const float* __restrict__ bhh0,
    const float* __restrict__ bih1,
    const float* __restrict__ bhh1,
    float* __restrict__ dout,
    unsigned short* __restrict__ A0,
    unsigned short* __restrict__ A1,
    int r)
{
  __shared__ __align__(16) unsigned char smem[57344];  // A:2x16KB, B:2x12KB; reduce:48KB

  const int wg = blockIdx.x;
  const int layer = wg >> 7;
  const bool active = layer ? (r >= 1) : (r < 512);
  if (!active) return;

  const int mh = wg & 1;
  const int c = (wg & 127) >> 1;
  const int R0 = mh * 64;
  const int J0 = c * 16;

  const int Ksz = layer ? K1 : K0;
  const int nch = Ksz / BK;                 // 8 or 16
  unsigned short* Ab = layer ? A1 : A0;
  const unsigned short* Wh = layer ? Whh1b : Whh0b;
  const unsigned short* Wx = Wih1b;         // only used by L1 (k>=1024)
  const bool first = layer ? (r == 1) : (r == 0);

  const int tid = threadIdx.x;
  const int w = tid >> 6;       // wave 0..3 — K-segment owner
  const int lane = tid & 63;
  const int lrow = lane >> 4;   // quad
  const int lcol = lane & 15;

  const int par = r & 1;
  const unsigned short* Acur = Ab + par * (Bsz * Ksz);
  unsigned short* Anext = Ab + (par ^ 1) * (Bsz * Ksz);

  const int col = J0 + lcol;
  const float* bhh = layer ? bhh1 : bhh0;
  const float bhr = bhh[col], bhz = bhh[1024 + col], bhn = bhh[2048 + col];
  const float bir = layer ? bih1[col] : 0.f;
  const float biz = layer ? bih1[1024 + col] : 0.f;
  const float bin = layer ? bih1[2048 + col] : 0.f;

  f32x4 ar[4], az[4], anh[4], anx[4];
#pragma unroll
  for (int f = 0; f < 4; ++f) {
    ar[f] = (f32x4){0.f, 0.f, 0.f, 0.f};
    az[f] = (f32x4){0.f, 0.f, 0.f, 0.f};
    anh[f] = (f32x4){0.f, 0.f, 0.f, 0.f};
    anx[f] = (f32x4){0.f, 0.f, 0.f, 0.f};
  }

  // first round: L0 skips everything (K is all-h); L1 skips h chunks (0..7)
  const int ch0 = first ? (layer ? 8 : nch) : 0;

  if (ch0 < nch) {
    short8 pa[4], pb[3];
    auto ld = [&](int ch) {
      const int k0 = ch * BK;
#pragma unroll
      for (int s = 0; s < 4; ++s) {
        const int idx = tid + s * 256, rowi = idx >> 4, k8 = idx & 15;
        pa[s] = *(const short8*)(Acur + (R0 + rowi) * Ksz + k0 + k8 * 8);
      }
#pragma unroll
      for (int s = 0; s < 3; ++s) {
        const int idx = tid + s * 256, tr = idx >> 4, k8 = idx & 15;
        const int wrow = (tr >> 4) * 1024 + J0 + (tr & 15);
        const unsigned short* gp = (k0 < 1024)
            ? (Wh + wrow * 1024 + k0 + k8 * 8)
            : (Wx + wrow * 1024 + (k0 - 1024) + k8 * 8);
        pb[s] = *(const short8*)gp;
      }
    };
    auto st = [&](int b) {
      unsigned short* sA = (unsigned short*)(smem + b * 16384);
      unsigned short* sB = (unsigned short*)(smem + 32768 + b * 12288);
#pragma unroll
      for (int s = 0; s < 4; ++s) {
        const int idx = tid + s * 256, rowi = idx >> 4, k8 = idx & 15;
        *(short8*)(sA + rowi * BK + k8 * 8) = pa[s];
      }
#pragma unroll
      for (int s = 0; s < 3; ++s) {
        const int idx = tid + s * 256, tr = idx >> 4, k8 = idx & 15;
        *(short8*)(sB + tr * BK + k8 * 8) = pb[s];
      }
    };

    ld(ch0); st(0);
    __syncthreads();

    for (int ch = ch0; ch < nch; ++ch) {
      const int b = (ch - ch0) & 1;
      const bool pf = (ch + 1 < nch);
      if (pf) ld(ch + 1);                       // prefetch to regs

      const unsigned short* sA = (const unsigned short*)(smem + b * 16384);
      const unsigned short* sB = (const unsigned short*)(smem + 32768 + b * 12288);
      const int ke = w * 32 + lrow * 8;         // this wave's K-segment
      short8 bfr = *(const short8*)(sB + (lcol) * BK + ke);
      short8 bfz = *(const short8*)(sB + (16 + lcol) * BK + ke);
      short8 bfn = *(const short8*)(sB + (32 + lcol) * BK + ke);
      const bool hp = (ch * BK) < 1024;
#pragma unroll
      for (int f = 0; f < 4; ++f) {
        short8 a = *(const short8*)(sA + (f * 16 + lcol) * BK + ke);
        ar[f] = __builtin_amdgcn_mfma_f32_16x16x32_bf16(a, bfr, ar[f], 0, 0, 0);
        az[f] = __builtin_amdgcn_mfma_f32_16x16x32_bf16(a, bfz, az[f], 0, 0, 0);
        if (hp) anh[f] = __builtin_amdgcn_mfma_f32_16x16x32_bf16(a, bfn, anh[f], 0, 0, 0);
        else    anx[f] = __builtin_amdgcn_mfma_f32_16x16x32_bf16(a, bfn, anx[f], 0, 0, 0);
      }
      if (pf) st(b ^ 1);                        // write next chunk's buffer
      __syncthreads();
    }
  }

  // ---- cross-wave K reduction (once per step): waves 1..3 dump, wave 0 sums
  f32x4* red = (f32x4*)smem;                    // 3 * 16 * 64 * 16B = 48 KB
  if (w > 0) {
    f32x4* dst = red + (w - 1) * 1024;
#pragma unroll
    for (int f = 0; f < 4; ++f) {
      dst[(0 * 4 + f) * 64 + lane] = ar[f];
      dst[(1 * 4 + f) * 64 + lane] = az[f];
      dst[(2 * 4 + f) * 64 + lane] = anh[f];
      dst[(3 * 4 + f) * 64 + lane] = anx[f];
    }
  }
  __syncthreads();
  if (w == 0) {
#pragma unroll
    for (int f = 0; f < 4; ++f) {
      ar[f]  += red[(0*4+f)*64+lane] + red[1024+(0*4+f)*64+lane] + red[2048+(0*4+f)*64+lane];
      az[f]  += red[(1*4+f)*64+lane] + red[1024+(1*4+f)*64+lane] + red[2048+(1*4+f)*64+lane];
      anh[f] += red[(2*4+f)*64+lane] + red[1024+(2*4+f)*64+lane] + red[2048+(2*4+f)*64+lane];
      anx[f] += red[(3*4+f)*64+lane] + red[1024+(3*4+f)*64+lane] + red[2048+(3*4+f)*64+lane];
    }

    const bool lastw = layer ? (r == 512) : (r == 511);
#pragma unroll
    for (int f = 0; f < 4; ++f) {
#pragma unroll
      for (int i = 0; i < 4; ++i) {
        const int row = R0 + f * 16 + lrow * 4 + i;
        float gr, gz, gn;                        // x-side additive
        if (layer == 0) {
          const int sv = src[row * Tlen + r];
          const float* pr = P + sv * 3072 + col;
          gr = pr[0]; gz = pr[1024]; gn = pr[2048];
        } else {
          gr = bir; gz = biz; gn = bin;
        }
        float rg = ar[f][i] + gr + bhr;
        rg = 1.f / (1.f + __expf(-rg));
        float zg = az[f][i] + gz + bhz;
        zg = 1.f / (1.f + __expf(-zg));
        const float ng = tanhf((anx[f][i] + gn) + rg * (anh[f][i] + bhn));
        const float hold = first ? 0.f : b2f(Acur[row * Ksz + col]);
        const float hnew = (1.f - zg) * ng + zg * hold;
        const unsigned short hb = f2b(hnew);
        Anext[row * Ksz + col] = hb;
        if (layer == 0) A1[(par ^ 1) * (Bsz * K1) + row * K1 + 1024 + col] = hb;
        if (lastw) dout[layer * (Bsz * Hd) + row * Hd + col] = hnew;
      }
    }
  }
}

// ---------------- prep: fp32 -> bf16 weight convert ----------------
__global__ void __launch_bounds__(256) cvt_k(const float* __restrict__ s,
                                            unsigned short* __restrict__ d, int n) {
  const int i = (blockIdx.x * 256 + threadIdx.x) * 8;
  if (i >= n) return;
  const float4 a = *(const float4*)(s + i);
  const float4 b = *(const float4*)(s + i + 4);
  short8 o;
  o[0] = (short)f2b(a.x); o[1] = (short)f2b(a.y);
  o[2] = (short)f2b(a.z); o[3] = (short)f2b(a.w);
  o[4] = (short)f2b(b.x); o[5] = (short)f2b(b.y);
  o[6] = (short)f2b(b.z); o[7] = (short)f2b(b.w);
  *(short8*)(d + i) = o;
}

// ---------------- prep: P = emb @ wih0^T + bih0 (fp32, exact path) ----------------
// grid (12, 8): g = bx*256+tid (3072), v-tile = by*64. acc[64] per thread.
__global__ void __launch_bounds__(256) pemb_k(const float* __restrict__ emb,
                                             const float* __restrict__ wih0,
                                             const float* __restrict__ bih0,
                                             float* __restrict__ P) {
  __shared__ float se[64 * 64];  // emb tile [vv][kk]
  const int g = blockIdx.x * 256 + threadIdx.x;
  const int v0 = blockIdx.y * 64;
  float acc[64];
#pragma unroll
  for (int i = 0; i < 64; ++i) acc[i] = 0.f;
  for (int kb = 0; kb < 8; ++kb) {
    __syncthreads();
#pragma unroll
    for (int s = 0; s < 4; ++s) {
      const int idx = threadIdx.x + s * 256;
      const int vv = idx >> 4, k4 = (idx & 15) * 4;
      *(float4*)(se + vv * 64 + k4) =
          *(const float4*)(emb + (v0 + vv) * 512 + kb * 64 + k4);
    }
    __syncthreads();
    float4 wv[16];
#pragma unroll
    for (int j = 0; j < 16; ++j)
      wv[j] = *(const float4*)(wih0 + g * 512 + kb * 64 + j * 4);
    for (int vv = 0; vv < 64; ++vv) {
      const float* er = se + vv * 64;
      float s0 = acc[vv];
#pragma unroll
      for (int j = 0; j < 16; ++j) {
        const float4 e = *(const float4*)(er + j * 4);
        s0 += wv[j].x * e.x + wv[j].y * e.y + wv[j].z * e.z + wv[j].w * e.w;
      }
      acc[vv] = s0;
    }
  }
  const float bb = bih0[g];
  for (int vv = 0; vv < 64; ++vv) P[(v0 + vv) * 3072 + g] = acc[vv] + bb;
}

extern "C" void kernel_launch(void* const* d_in, const int* in_sizes, int n_in,
                              void* d_out, int out_size, void* d_ws, size_t ws_size,
                              hipStream_t stream) {
  const int* src = (const int*)d_in[0];
  const float* emb = (const float*)d_in[1];
  const float* wih0 = (const float*)d_in[2];
  const float* whh0 = (const float*)d_in[3];
  const float* bih0 = (const float*)d_in[4];
  const float* bhh0 = (const float*)d_in[5];
  const float* wih1 = (const float*)d_in[6];
  const float* whh1 = (const float*)d_in[7];
  const float* bih1 = (const float*)d_in[8];
  const float* bhh1 = (const float*)d_in[9];
  float* dout = (float*)d_out;

  char* p = (char*)d_ws;
  unsigned short* A0 = (unsigned short*)p;                       // 524288 B
  unsigned short* A1 = (unsigned short*)(p + 524288);            // 1048576 B
  unsigned short* Whh0b = (unsigned short*)(p + 1572864);        // 6291456 B
  unsigned short* Whh1b = (unsigned short*)(p + 7864320);        // 6291456 B
  unsigned short* Wih1b = (unsigned short*)(p + 14155776);       // 6291456 B
  float* P = (float*)(p + 20447232);                             // 6291456 B
  // total ws use: 26738688 B (~25.5 MB)

  constexpr int NW = 3072 * 1024;  // elements per weight matrix
  hipLaunchKernelGGL(cvt_k, dim3(NW / (256 * 8)), dim3(256), 0, stream, whh0, Whh0b, NW);
  hipLaunchKernelGGL(cvt_k, dim3(NW / (256 * 8)), dim3(256), 0, stream, whh1, Whh1b, NW);
  hipLaunchKernelGGL(cvt_k, dim3(NW / (256 * 8)), dim3(256), 0, stream, wih1, Wih1b, NW);
  hipLaunchKernelGGL(pemb_k, dim3(12, 8), dim3(256), 0, stream, emb, wih0, bih0, P);

  for (int r = 0; r < 513; ++r) {
    hipLaunchKernelGGL(gru_step, dim3(256), dim3(256), 0, stream,
                       src, P, Whh0b, Whh1b, Wih1b, bhh0, bih1, bhh1,
                       dout, A0, A1, r);
  }
}